// Round 1
// 202.054 us; speedup vs baseline: 1.0068x; 1.0068x over previous
//
#include <hip/hip_runtime.h>
#include <math.h>

#define BS 16
#define SS 2048
#define HH 1024
#define DD 32
#define CC 8
#define LL 3

// 4 partial blocks per (b,d) span, 256 threads each; thread t owns float4-col t.
// Rows interleaved mod 4 across the 4 partial blocks; 4-deep unrolled load
// pipeline (independent float4 loads, 2 accumulators). Each block projects its
// (1/cnt)-scaled partial row-sum through W[c] down to 3 floats and writes one
// 3-float partial logit to workspace. No inter-rowgroup LDS fold, no big-block
// barrier tail. logits are linear in the row-sum, so partials add exactly.
__global__ __launch_bounds__(256, 8) void pool_partial_kernel(
    const float* __restrict__ enc,   // (BS,S,H)
    const float* __restrict__ W,     // (C,H,L)
    const int*   __restrict__ head,  // (BS,D)
    const int*   __restrict__ tail,  // (BS,D)
    const int*   __restrict__ dt,    // (BS,D)
    float* __restrict__ partials)    // (BS*D, 4, 3) in d_ws
{
    const int blk  = blockIdx.x;          // 0 .. BS*DD*4-1
    const int bd   = blk >> 2;
    const int part = blk & 3;
    const int b    = bd >> 5;             // DD = 32
    const int s0   = head[bd] + 1;
    const int s1   = tail[bd];
    const int c    = dt[bd];
    const int tid  = threadIdx.x;         // 0..255
    const int col  = tid << 2;

    const float* base = enc + ((size_t)b * SS) * HH + col;

    float4 a0 = make_float4(0.f, 0.f, 0.f, 0.f);
    float4 a1 = a0;

    // rows congruent to (s0+part) mod 4, 4 loads in flight per iteration
    int s = s0 + part;
    for (; s + 12 < s1; s += 16) {
        float4 v0 = *(const float4*)(base + (size_t)(s     ) * HH);
        float4 v1 = *(const float4*)(base + (size_t)(s +  4) * HH);
        float4 v2 = *(const float4*)(base + (size_t)(s +  8) * HH);
        float4 v3 = *(const float4*)(base + (size_t)(s + 12) * HH);
        a0.x += v0.x; a0.y += v0.y; a0.z += v0.z; a0.w += v0.w;
        a1.x += v1.x; a1.y += v1.y; a1.z += v1.z; a1.w += v1.w;
        a0.x += v2.x; a0.y += v2.y; a0.z += v2.z; a0.w += v2.w;
        a1.x += v3.x; a1.y += v3.y; a1.z += v3.z; a1.w += v3.w;
    }
    for (; s < s1; s += 4) {
        float4 v = *(const float4*)(base + (size_t)s * HH);
        a0.x += v.x; a0.y += v.y; a0.z += v.z; a0.w += v.w;
    }

    const int   cnt = s1 - s0;
    const float inv = (cnt > 0) ? (1.0f / (float)cnt) : 0.0f;
    const float px = (a0.x + a1.x) * inv;
    const float py = (a0.y + a1.y) * inv;
    const float pz = (a0.z + a1.z) * inv;
    const float pw = (a0.w + a1.w) * inv;

    // project this thread's 4 columns through W[c]
    const float* wp = W + ((size_t)c * HH + col) * LL;
    float l0 = px * wp[0] + py * wp[3] + pz * wp[6] + pw * wp[9];
    float l1 = px * wp[1] + py * wp[4] + pz * wp[7] + pw * wp[10];
    float l2 = px * wp[2] + py * wp[5] + pz * wp[8] + pw * wp[11];

    #pragma unroll
    for (int off = 32; off >= 1; off >>= 1) {
        l0 += __shfl_down(l0, off, 64);
        l1 += __shfl_down(l1, off, 64);
        l2 += __shfl_down(l2, off, 64);
    }
    __shared__ float ws[4][3];
    const int lane = tid & 63, wv = tid >> 6;
    if (lane == 0) { ws[wv][0] = l0; ws[wv][1] = l1; ws[wv][2] = l2; }
    __syncthreads();
    if (tid == 0) {
        float r0 = ws[0][0] + ws[1][0] + ws[2][0] + ws[3][0];
        float r1 = ws[0][1] + ws[1][1] + ws[2][1] + ws[3][1];
        float r2 = ws[0][2] + ws[1][2] + ws[2][2] + ws[3][2];
        partials[blk * 3 + 0] = r0;
        partials[blk * 3 + 1] = r1;
        partials[blk * 3 + 2] = r2;
    }
}

// Single block, 512 threads: one thread per (b,d). Gather the 4 partial logit
// triples (one contiguous 48B read), add bias, emit logits + masked-mean NLL.
__global__ __launch_bounds__(512) void loss_kernel(
    const float* __restrict__ partials, // (BS*D, 4, 3)
    const float* __restrict__ bias,     // (C,L)
    const int*   __restrict__ dt,       // (BS*D)
    const int*   __restrict__ labels,   // (BS*D)
    float* __restrict__ out)            // logits (BS*D*L) then loss (1)
{
    const int i = threadIdx.x;          // 0..511 == BS*DD-1
    const int c = dt[i];
    const float4* p = (const float4*)(partials + (size_t)i * 12);
    const float4 q0 = p[0], q1 = p[1], q2 = p[2];
    // elements [0..11] = (part0: l0 l1 l2, part1: l0 l1 l2, ...)
    const float x0 = q0.x + q0.w + q1.z + q2.y + bias[c * LL + 0];
    const float x1 = q0.y + q1.x + q1.w + q2.z + bias[c * LL + 1];
    const float x2 = q0.z + q1.y + q2.x + q2.w + bias[c * LL + 2];
    out[i * LL + 0] = x0;
    out[i * LL + 1] = x1;
    out[i * LL + 2] = x2;

    float nll = 0.f, v = 0.f;
    {
        const int lab = labels[i];
        const float m   = fmaxf(x0, fmaxf(x1, x2));
        const float lse = m + logf(expf(x0 - m) + expf(x1 - m) + expf(x2 - m));
        if (lab >= 0) {
            const float xl = (lab == 0) ? x0 : ((lab == 1) ? x1 : x2);
            nll = lse - xl;
            v   = 1.f;
        }
    }
    #pragma unroll
    for (int off = 32; off >= 1; off >>= 1) {
        nll += __shfl_down(nll, off, 64);
        v   += __shfl_down(v,   off, 64);
    }
    __shared__ float sn[8], sv[8];
    const int lane = i & 63, wv = i >> 6;
    if (lane == 0) { sn[wv] = nll; sv[wv] = v; }
    __syncthreads();
    if (i == 0) {
        float tn = 0.f, tv = 0.f;
        #pragma unroll
        for (int w = 0; w < 8; ++w) { tn += sn[w]; tv += sv[w]; }
        out[BS * DD * LL] = (tv > 0.f) ? (tn / tv) : 0.f;
    }
}

extern "C" void kernel_launch(void* const* d_in, const int* in_sizes, int n_in,
                              void* d_out, int out_size, void* d_ws, size_t ws_size,
                              hipStream_t stream) {
    const float* enc    = (const float*)d_in[0];   // (16,2048,1024) f32
    const float* W      = (const float*)d_in[1];   // (8,1024,3) f32
    const float* bias   = (const float*)d_in[2];   // (8,3) f32
    const int*   head   = (const int*)d_in[3];     // (16,32) i32
    const int*   tail   = (const int*)d_in[4];     // (16,32) i32
    const int*   dt     = (const int*)d_in[5];     // (16,32) i32
    const int*   labels = (const int*)d_in[6];     // (16,32) i32
    float* out      = (float*)d_out;               // logits (1536) + loss (1)
    float* partials = (float*)d_ws;                // 2048*3 floats = 24 KB

    pool_partial_kernel<<<BS * DD * 4, 256, 0, stream>>>(enc, W, head, tail, dt, partials);
    loss_kernel<<<1, 512, 0, stream>>>(partials, bias, dt, labels, out);
}